// Round 2
// baseline (786.145 us; speedup 1.0000x reference)
//
#include <hip/hip_runtime.h>
#include <math.h>

#define ITERS 14

// ---------------------------------------------------------------------------
// Kernel A: P = l2_normalize(X @ W^T + b) for both matrices.
// grid (128, 2), block 256 (16x16 thread grid, 4x4 micro-tile -> 64x64 tile).
// LDS is k-major (xs[k][row], ws[k][col], pad 68) so the inner loop is
// 2 ds_read_b128 + 16 FMA per k (VALU-bound).
// Outputs: subP row-major [8192][64]; edgeT TRANSPOSED [64][8192] so the
// fused kernel's B loads coalesce (lane-contiguous cols at fixed k).
// ---------------------------------------------------------------------------
__global__ __launch_bounds__(256) void proj_norm_kernel(
    const float* __restrict__ Xsub, const float* __restrict__ Xedge,
    const float* __restrict__ Wsub, const float* __restrict__ bsub,
    const float* __restrict__ Wedge, const float* __restrict__ bedge,
    float* __restrict__ subP, float* __restrict__ edgeT)
{
    const int mat = blockIdx.y;
    const float* X  = mat ? Xedge : Xsub;
    const float* W  = mat ? Wedge : Wsub;
    const float* Bv = mat ? bedge : bsub;

    const int r0 = blockIdx.x * 64;
    const int t  = threadIdx.x;
    const int tx = t & 15, ty = t >> 4;

    __shared__ float xs[64 * 68];   // [k][row+pad]
    __shared__ float ws[64 * 68];   // [k][col+pad]
    __shared__ float tr[64 * 68];   // transpose staging for edgeT

    float acc[4][4] = {};

    for (int ch = 0; ch < 8; ++ch) {
        const int kb = ch * 64;
#pragma unroll
        for (int i = 0; i < 4; ++i) {
            int e = t + 256 * i;         // 1024 float4 per operand
            int row = e & 63, kq = e >> 6;
            float4 xv = *(const float4*)(X + (size_t)(r0 + row) * 512 + kb + kq * 4);
            xs[(kq * 4 + 0) * 68 + row] = xv.x;
            xs[(kq * 4 + 1) * 68 + row] = xv.y;
            xs[(kq * 4 + 2) * 68 + row] = xv.z;
            xs[(kq * 4 + 3) * 68 + row] = xv.w;
            float4 wv = *(const float4*)(W + (size_t)row * 512 + kb + kq * 4);
            ws[(kq * 4 + 0) * 68 + row] = wv.x;
            ws[(kq * 4 + 1) * 68 + row] = wv.y;
            ws[(kq * 4 + 2) * 68 + row] = wv.z;
            ws[(kq * 4 + 3) * 68 + row] = wv.w;
        }
        __syncthreads();
#pragma unroll 8
        for (int k = 0; k < 64; ++k) {
            const float4 a4 = *(const float4*)&xs[k * 68 + ty * 4];
            const float4 b4 = *(const float4*)&ws[k * 68 + tx * 4];
            const float av[4] = {a4.x, a4.y, a4.z, a4.w};
#pragma unroll
            for (int i = 0; i < 4; ++i) {
                acc[i][0] = fmaf(av[i], b4.x, acc[i][0]);
                acc[i][1] = fmaf(av[i], b4.y, acc[i][1]);
                acc[i][2] = fmaf(av[i], b4.z, acc[i][2]);
                acc[i][3] = fmaf(av[i], b4.w, acc[i][3]);
            }
        }
        __syncthreads();
    }

    // bias + rowwise l2 norm. A row's 64 cols live in one wave (tx = lane&15),
    // so shfl_xor over lane bits 0..3 reduces across the row.
    const float4 bb = *(const float4*)(Bv + tx * 4);
    float ss[4];
#pragma unroll
    for (int i = 0; i < 4; ++i) {
        acc[i][0] += bb.x; acc[i][1] += bb.y; acc[i][2] += bb.z; acc[i][3] += bb.w;
        float s = acc[i][0]*acc[i][0] + acc[i][1]*acc[i][1]
                + acc[i][2]*acc[i][2] + acc[i][3]*acc[i][3];
#pragma unroll
        for (int off = 1; off <= 8; off <<= 1)
            s += __shfl_xor(s, off, 64);
        ss[i] = s;
    }

    if (mat == 0) {
#pragma unroll
        for (int i = 0; i < 4; ++i) {
            const float inv = 1.0f / fmaxf(sqrtf(ss[i]), 1e-12f);
            float4 o;
            o.x = acc[i][0]*inv; o.y = acc[i][1]*inv; o.z = acc[i][2]*inv; o.w = acc[i][3]*inv;
            *(float4*)(subP + (size_t)(r0 + ty * 4 + i) * 64 + tx * 4) = o;
        }
    } else {
        __syncthreads();   // done with ws/xs readers before (tr separate, but keep order clean)
#pragma unroll
        for (int i = 0; i < 4; ++i) {
            const float inv = 1.0f / fmaxf(sqrtf(ss[i]), 1e-12f);
#pragma unroll
            for (int j = 0; j < 4; ++j)
                tr[(tx * 4 + j) * 68 + ty * 4 + i] = acc[i][j] * inv;   // tr[col][row]
        }
        __syncthreads();
#pragma unroll
        for (int i = 0; i < 4; ++i) {
            int e = t + 256 * i;            // 1024 float4: 64 cols x 16 row-quads
            int c = e >> 4, rq = e & 15;
            *(float4*)(edgeT + (size_t)c * 8192 + r0 + rq * 4) =
                *(const float4*)&tr[c * 68 + rq * 4];
        }
    }
}

// ---------------------------------------------------------------------------
// Kernel B (fused): scores GEMM + 1.5-entmax, z never touches HBM.
// grid 1024, block 1024 (16 waves). Block = 8 rows x 8192 cols; thread owns
// 8 rows x 8 cols (cols 4t..4t+3 and 4096+4t..+3) = 64 z in registers.
// B operand read from L2 (edgeT k-major, 2 MB, XCD-L2 resident).
// Newton for tau: per-wave shfl reduce of (f[8],g[8]) -> 16x16 LDS table ->
// 8 threads finalize. Waves with no support for any row skip the scan
// (tau is monotone increasing -> once inactive, always inactive).
// ---------------------------------------------------------------------------
#define FMA4(ACC, S, B) \
    ACC.x = fmaf(S, B.x, ACC.x); ACC.y = fmaf(S, B.y, ACC.y); \
    ACC.z = fmaf(S, B.z, ACC.z); ACC.w = fmaf(S, B.w, ACC.w);

__global__ __launch_bounds__(1024, 4) void fused_score_entmax_kernel(
    const float* __restrict__ subP, const float* __restrict__ edgeT,
    const float* __restrict__ log_scale, float* __restrict__ out)
{
    const int t    = threadIdx.x;
    const int lane = t & 63;
    const int wid  = t >> 6;
    const int r0   = blockIdx.x * 8;
    const int c0   = t * 4;          // cols c0..c0+3 and c0+4096..+3

    __shared__ float asT[64 * 8];    // A transposed: asT[k][r]
    __shared__ float tbl[16 * 16];   // per-wave reduce table
    __shared__ float tauL[8];

    if (t < 512) {
        int r = t >> 6, k = t & 63;
        asT[k * 8 + r] = subP[(size_t)(r0 + r) * 64 + k];
    }
    __syncthreads();

    float4 acc0[8], acc1[8];
#pragma unroll
    for (int r = 0; r < 8; ++r) {
        acc0[r] = make_float4(0.f, 0.f, 0.f, 0.f);
        acc1[r] = make_float4(0.f, 0.f, 0.f, 0.f);
    }

#pragma unroll 2
    for (int k = 0; k < 64; ++k) {
        const float4 b0 = *(const float4*)(edgeT + (size_t)k * 8192 + c0);
        const float4 b1 = *(const float4*)(edgeT + (size_t)k * 8192 + c0 + 4096);
        const float4 a0 = *(const float4*)&asT[k * 8];
        const float4 a1 = *(const float4*)&asT[k * 8 + 4];
        FMA4(acc0[0], a0.x, b0); FMA4(acc1[0], a0.x, b1);
        FMA4(acc0[1], a0.y, b0); FMA4(acc1[1], a0.y, b1);
        FMA4(acc0[2], a0.z, b0); FMA4(acc1[2], a0.z, b1);
        FMA4(acc0[3], a0.w, b0); FMA4(acc1[3], a0.w, b1);
        FMA4(acc0[4], a1.x, b0); FMA4(acc1[4], a1.x, b1);
        FMA4(acc0[5], a1.y, b0); FMA4(acc1[5], a1.y, b1);
        FMA4(acc0[6], a1.z, b0); FMA4(acc1[6], a1.z, b1);
        FMA4(acc0[7], a1.w, b0); FMA4(acc1[7], a1.w, b1);
    }

    float sc = expf(log_scale[0]);
    sc = fminf(fmaxf(sc, 0.5f), 20.0f);
    const float zs = sc * 0.5f;      // z = scores/2
#pragma unroll
    for (int r = 0; r < 8; ++r) {
        acc0[r].x *= zs; acc0[r].y *= zs; acc0[r].z *= zs; acc0[r].w *= zs;
        acc1[r].x *= zs; acc1[r].y *= zs; acc1[r].z *= zs; acc1[r].w *= zs;
    }

    // ---- per-row wave max (wlm) + block max -> tau0 = m - 1 ----
    float wlm[8];
#pragma unroll
    for (int r = 0; r < 8; ++r) {
        float m = fmaxf(fmaxf(fmaxf(acc0[r].x, acc0[r].y), fmaxf(acc0[r].z, acc0[r].w)),
                        fmaxf(fmaxf(acc1[r].x, acc1[r].y), fmaxf(acc1[r].z, acc1[r].w)));
#pragma unroll
        for (int off = 32; off; off >>= 1)
            m = fmaxf(m, __shfl_xor(m, off, 64));
        wlm[r] = m;                  // wave-uniform
    }
    if (lane == 0) {
#pragma unroll
        for (int r = 0; r < 8; ++r) tbl[wid * 16 + r] = wlm[r];
    }
    __syncthreads();
    if (t < 8) {
        float m = -1e30f;
#pragma unroll
        for (int w = 0; w < 16; ++w) m = fmaxf(m, tbl[w * 16 + t]);
        tauL[t] = m - 1.0f;          // f(tau0) >= 1 (max element alone gives 1)
    }
    __syncthreads();

    float tau[8];
    {
        const float4 tA = *(const float4*)&tauL[0];
        const float4 tB = *(const float4*)&tauL[4];
        tau[0]=tA.x; tau[1]=tA.y; tau[2]=tA.z; tau[3]=tA.w;
        tau[4]=tB.x; tau[5]=tB.y; tau[6]=tB.z; tau[7]=tB.w;
    }

    for (int it = 0; it < ITERS; ++it) {
        bool active = false;
#pragma unroll
        for (int r = 0; r < 8; ++r) active |= (wlm[r] > tau[r]);
        if (active) {                // wave-uniform branch
            float fv[8], gv[8];
#pragma unroll
            for (int r = 0; r < 8; ++r) {
                float f = 0.f, g = 0.f, d;
                d = fmaxf(acc0[r].x - tau[r], 0.f); f = fmaf(d, d, f); g += d;
                d = fmaxf(acc0[r].y - tau[r], 0.f); f = fmaf(d, d, f); g += d;
                d = fmaxf(acc0[r].z - tau[r], 0.f); f = fmaf(d, d, f); g += d;
                d = fmaxf(acc0[r].w - tau[r], 0.f); f = fmaf(d, d, f); g += d;
                d = fmaxf(acc1[r].x - tau[r], 0.f); f = fmaf(d, d, f); g += d;
                d = fmaxf(acc1[r].y - tau[r], 0.f); f = fmaf(d, d, f); g += d;
                d = fmaxf(acc1[r].z - tau[r], 0.f); f = fmaf(d, d, f); g += d;
                d = fmaxf(acc1[r].w - tau[r], 0.f); f = fmaf(d, d, f); g += d;
                fv[r] = f; gv[r] = g;
            }
#pragma unroll
            for (int off = 32; off; off >>= 1) {
#pragma unroll
                for (int r = 0; r < 8; ++r) {
                    fv[r] += __shfl_xor(fv[r], off, 64);
                    gv[r] += __shfl_xor(gv[r], off, 64);
                }
            }
            if (lane == 0) {
#pragma unroll
                for (int r = 0; r < 8; ++r) {
                    tbl[wid * 16 + r]     = fv[r];
                    tbl[wid * 16 + 8 + r] = gv[r];
                }
            }
        } else if (lane == 0) {
#pragma unroll
            for (int i = 0; i < 16; ++i) tbl[wid * 16 + i] = 0.f;
        }
        __syncthreads();
        if (t < 8) {
            float F = 0.f, G = 0.f;
#pragma unroll
            for (int w = 0; w < 16; ++w) {
                F += tbl[w * 16 + t];
                G += tbl[w * 16 + 8 + t];
            }
            // G >= m - tau > 0 (tau stays strictly below the row max)
            tauL[t] += (F - 1.0f) / (2.0f * G);
        }
        __syncthreads();
        {
            const float4 tA = *(const float4*)&tauL[0];
            const float4 tB = *(const float4*)&tauL[4];
            tau[0]=tA.x; tau[1]=tA.y; tau[2]=tA.z; tau[3]=tA.w;
            tau[4]=tB.x; tau[5]=tB.y; tau[6]=tB.z; tau[7]=tB.w;
        }
    }

    // ---- p = max(z - tau, 0)^2, write once ----
#pragma unroll
    for (int r = 0; r < 8; ++r) {
        float* op = out + (size_t)(r0 + r) * 8192;
        float4 p0, p1; float d;
        d = fmaxf(acc0[r].x - tau[r], 0.f); p0.x = d * d;
        d = fmaxf(acc0[r].y - tau[r], 0.f); p0.y = d * d;
        d = fmaxf(acc0[r].z - tau[r], 0.f); p0.z = d * d;
        d = fmaxf(acc0[r].w - tau[r], 0.f); p0.w = d * d;
        d = fmaxf(acc1[r].x - tau[r], 0.f); p1.x = d * d;
        d = fmaxf(acc1[r].y - tau[r], 0.f); p1.y = d * d;
        d = fmaxf(acc1[r].z - tau[r], 0.f); p1.z = d * d;
        d = fmaxf(acc1[r].w - tau[r], 0.f); p1.w = d * d;
        *(float4*)(op + c0)        = p0;
        *(float4*)(op + c0 + 4096) = p1;
    }
}

// ---------------------------------------------------------------------------
extern "C" void kernel_launch(void* const* d_in, const int* in_sizes, int n_in,
                              void* d_out, int out_size, void* d_ws, size_t ws_size,
                              hipStream_t stream)
{
    const float* edge_repr = (const float*)d_in[0];
    const float* sub_repr  = (const float*)d_in[1];
    const float* W_sub     = (const float*)d_in[2];
    const float* b_sub     = (const float*)d_in[3];
    const float* W_edge    = (const float*)d_in[4];
    const float* b_edge    = (const float*)d_in[5];
    const float* log_scale = (const float*)d_in[6];
    float* out = (float*)d_out;

    float* sub_proj = (float*)d_ws;                      // [8192][64]  row-major
    float* edgeT    = (float*)d_ws + (size_t)8192 * 64;  // [64][8192]  k-major

    proj_norm_kernel<<<dim3(128, 2), 256, 0, stream>>>(
        sub_repr, edge_repr, W_sub, b_sub, W_edge, b_edge, sub_proj, edgeT);

    fused_score_entmax_kernel<<<1024, 1024, 0, stream>>>(
        sub_proj, edgeT, log_scale, out);
}

// Round 3
// 706.578 us; speedup vs baseline: 1.1126x; 1.1126x over previous
//
#include <hip/hip_runtime.h>
#include <math.h>

#define ITERS 12

// ---------------------------------------------------------------------------
// Kernel A: P = l2_normalize(X @ W^T + b) for both matrices (unchanged r2).
// Outputs: subP row-major [8192][64]; edgeT TRANSPOSED [64][8192].
// ---------------------------------------------------------------------------
__global__ __launch_bounds__(256) void proj_norm_kernel(
    const float* __restrict__ Xsub, const float* __restrict__ Xedge,
    const float* __restrict__ Wsub, const float* __restrict__ bsub,
    const float* __restrict__ Wedge, const float* __restrict__ bedge,
    float* __restrict__ subP, float* __restrict__ edgeT)
{
    const int mat = blockIdx.y;
    const float* X  = mat ? Xedge : Xsub;
    const float* W  = mat ? Wedge : Wsub;
    const float* Bv = mat ? bedge : bsub;

    const int r0 = blockIdx.x * 64;
    const int t  = threadIdx.x;
    const int tx = t & 15, ty = t >> 4;

    __shared__ float xs[64 * 68];
    __shared__ float ws[64 * 68];
    __shared__ float tr[64 * 68];

    float acc[4][4] = {};

    for (int ch = 0; ch < 8; ++ch) {
        const int kb = ch * 64;
#pragma unroll
        for (int i = 0; i < 4; ++i) {
            int e = t + 256 * i;
            int row = e & 63, kq = e >> 6;
            float4 xv = *(const float4*)(X + (size_t)(r0 + row) * 512 + kb + kq * 4);
            xs[(kq * 4 + 0) * 68 + row] = xv.x;
            xs[(kq * 4 + 1) * 68 + row] = xv.y;
            xs[(kq * 4 + 2) * 68 + row] = xv.z;
            xs[(kq * 4 + 3) * 68 + row] = xv.w;
            float4 wv = *(const float4*)(W + (size_t)row * 512 + kb + kq * 4);
            ws[(kq * 4 + 0) * 68 + row] = wv.x;
            ws[(kq * 4 + 1) * 68 + row] = wv.y;
            ws[(kq * 4 + 2) * 68 + row] = wv.z;
            ws[(kq * 4 + 3) * 68 + row] = wv.w;
        }
        __syncthreads();
#pragma unroll 8
        for (int k = 0; k < 64; ++k) {
            const float4 a4 = *(const float4*)&xs[k * 68 + ty * 4];
            const float4 b4 = *(const float4*)&ws[k * 68 + tx * 4];
            const float av[4] = {a4.x, a4.y, a4.z, a4.w};
#pragma unroll
            for (int i = 0; i < 4; ++i) {
                acc[i][0] = fmaf(av[i], b4.x, acc[i][0]);
                acc[i][1] = fmaf(av[i], b4.y, acc[i][1]);
                acc[i][2] = fmaf(av[i], b4.z, acc[i][2]);
                acc[i][3] = fmaf(av[i], b4.w, acc[i][3]);
            }
        }
        __syncthreads();
    }

    const float4 bb = *(const float4*)(Bv + tx * 4);
    float ss[4];
#pragma unroll
    for (int i = 0; i < 4; ++i) {
        acc[i][0] += bb.x; acc[i][1] += bb.y; acc[i][2] += bb.z; acc[i][3] += bb.w;
        float s = acc[i][0]*acc[i][0] + acc[i][1]*acc[i][1]
                + acc[i][2]*acc[i][2] + acc[i][3]*acc[i][3];
#pragma unroll
        for (int off = 1; off <= 8; off <<= 1)
            s += __shfl_xor(s, off, 64);
        ss[i] = s;
    }

    if (mat == 0) {
#pragma unroll
        for (int i = 0; i < 4; ++i) {
            const float inv = 1.0f / fmaxf(sqrtf(ss[i]), 1e-12f);
            float4 o;
            o.x = acc[i][0]*inv; o.y = acc[i][1]*inv; o.z = acc[i][2]*inv; o.w = acc[i][3]*inv;
            *(float4*)(subP + (size_t)(r0 + ty * 4 + i) * 64 + tx * 4) = o;
        }
    } else {
        __syncthreads();
#pragma unroll
        for (int i = 0; i < 4; ++i) {
            const float inv = 1.0f / fmaxf(sqrtf(ss[i]), 1e-12f);
#pragma unroll
            for (int j = 0; j < 4; ++j)
                tr[(tx * 4 + j) * 68 + ty * 4 + i] = acc[i][j] * inv;
        }
        __syncthreads();
#pragma unroll
        for (int i = 0; i < 4; ++i) {
            int e = t + 256 * i;
            int c = e >> 4, rq = e & 15;
            *(float4*)(edgeT + (size_t)c * 8192 + r0 + rq * 4) =
                *(const float4*)&tr[c * 68 + rq * 4];
        }
    }
}

// ---------------------------------------------------------------------------
// Kernel B (fused v2): scores GEMM + exact 1.5-entmax via support-set
// iteration. Block = 8 rows x 8192 cols, 1024 threads. Thread owns 64 z:
// 52 in registers (accA rows 3..7 half0, accB rows 0..7 half1), 12 in LDS
// (rows 0..2 half0) to keep peak VGPR ~85 (no unified-file overflow).
// tau iteration: S = {z > tau}; solve n*tau^2 - 2*s1*tau + (s2-1) = 0,
// minus root (== reference's mean - sqrt(delta)). Monotone from below;
// exact once support stabilizes -> bit-identical tau -> uniform break.
// Newton fallback when discriminant < 0.
// ---------------------------------------------------------------------------
#define FMA4(ACC, S, B) \
    ACC.x = fmaf(S, B.x, ACC.x); ACC.y = fmaf(S, B.y, ACC.y); \
    ACC.z = fmaf(S, B.z, ACC.z); ACC.w = fmaf(S, B.w, ACC.w);

#define HMAX4(V) fmaxf(fmaxf(V.x, V.y), fmaxf(V.z, V.w))

#define SCAN_ELEM(E, TAU) { \
    const float e_ = (E); \
    const bool p_ = e_ > (TAU); \
    const float zm_ = p_ ? e_ : 0.0f; \
    n  += p_ ? 1.0f : 0.0f; \
    s1 += zm_; \
    s2 = fmaf(zm_, e_, s2); }

#define SCAN_F4(V, TAU) { \
    SCAN_ELEM(V.x, TAU); SCAN_ELEM(V.y, TAU); \
    SCAN_ELEM(V.z, TAU); SCAN_ELEM(V.w, TAU); }

#define P2_F4(SRC, DST, TAU) { \
    float d_; \
    d_ = fmaxf(SRC.x - (TAU), 0.0f); DST.x = d_ * d_; \
    d_ = fmaxf(SRC.y - (TAU), 0.0f); DST.y = d_ * d_; \
    d_ = fmaxf(SRC.z - (TAU), 0.0f); DST.z = d_ * d_; \
    d_ = fmaxf(SRC.w - (TAU), 0.0f); DST.w = d_ * d_; }

__global__ __launch_bounds__(1024, 4) void fused_score_entmax_kernel(
    const float* __restrict__ subP, const float* __restrict__ edgeT,
    const float* __restrict__ log_scale, float* __restrict__ out)
{
    const int t    = threadIdx.x;
    const int lane = t & 63;
    const int wid  = t >> 6;
    const int r0   = blockIdx.x * 8;
    const int c0   = t * 4;

    __shared__ float zL[3 * 4096];   // rows 0..2, half0: 48 KB, thread-private slices
    __shared__ float asT[64 * 8];    // A fragment, k-major
    __shared__ float tbl[16 * 24];   // per-wave reduce table (n,s1,s2 x 8 rows)
    __shared__ float tauS[8];

    if (t < 512) {
        int r = t >> 6, k = t & 63;
        asT[k * 8 + r] = subP[(size_t)(r0 + r) * 64 + k];
    }
    __syncthreads();

    float sc = expf(log_scale[0]);
    sc = fminf(fmaxf(sc, 0.5f), 20.0f);
    const float zs = sc * 0.5f;      // z = scores/2

    // ---- GEMM pass 1: col-half 0 (cols c0) ----
    float4 acc[8];
#pragma unroll
    for (int r = 0; r < 8; ++r) acc[r] = make_float4(0.f, 0.f, 0.f, 0.f);
#pragma unroll 4
    for (int k = 0; k < 64; ++k) {
        const float4 b4 = *(const float4*)(edgeT + (size_t)k * 8192 + c0);
        const float4 a0 = *(const float4*)&asT[k * 8];
        const float4 a1 = *(const float4*)&asT[k * 8 + 4];
        FMA4(acc[0], a0.x, b4); FMA4(acc[1], a0.y, b4);
        FMA4(acc[2], a0.z, b4); FMA4(acc[3], a0.w, b4);
        FMA4(acc[4], a1.x, b4); FMA4(acc[5], a1.y, b4);
        FMA4(acc[6], a1.z, b4); FMA4(acc[7], a1.w, b4);
    }
    float pm[8];
#pragma unroll
    for (int r = 0; r < 8; ++r) {
        acc[r].x *= zs; acc[r].y *= zs; acc[r].z *= zs; acc[r].w *= zs;
        pm[r] = HMAX4(acc[r]);
    }
    // rows 0..2 -> LDS, rows 3..7 stay in registers
    *(float4*)&zL[0 * 4096 + c0] = acc[0];
    *(float4*)&zL[1 * 4096 + c0] = acc[1];
    *(float4*)&zL[2 * 4096 + c0] = acc[2];
    float4 accA[5];
#pragma unroll
    for (int r = 0; r < 5; ++r) accA[r] = acc[r + 3];

    // ---- GEMM pass 2: col-half 1 (cols c0 + 4096) ----
    float4 accB[8];
#pragma unroll
    for (int r = 0; r < 8; ++r) accB[r] = make_float4(0.f, 0.f, 0.f, 0.f);
#pragma unroll 4
    for (int k = 0; k < 64; ++k) {
        const float4 b4 = *(const float4*)(edgeT + (size_t)k * 8192 + c0 + 4096);
        const float4 a0 = *(const float4*)&asT[k * 8];
        const float4 a1 = *(const float4*)&asT[k * 8 + 4];
        FMA4(accB[0], a0.x, b4); FMA4(accB[1], a0.y, b4);
        FMA4(accB[2], a0.z, b4); FMA4(accB[3], a0.w, b4);
        FMA4(accB[4], a1.x, b4); FMA4(accB[5], a1.y, b4);
        FMA4(accB[6], a1.z, b4); FMA4(accB[7], a1.w, b4);
    }
#pragma unroll
    for (int r = 0; r < 8; ++r) {
        accB[r].x *= zs; accB[r].y *= zs; accB[r].z *= zs; accB[r].w *= zs;
        pm[r] = fmaxf(pm[r], HMAX4(accB[r]));
    }

    // ---- per-row block max -> tau0 = max - 1 ----
#pragma unroll
    for (int r = 0; r < 8; ++r) {
#pragma unroll
        for (int off = 32; off; off >>= 1)
            pm[r] = fmaxf(pm[r], __shfl_xor(pm[r], off, 64));
    }
    if (lane == 0) {
#pragma unroll
        for (int r = 0; r < 8; ++r) tbl[wid * 24 + r] = pm[r];
    }
    __syncthreads();
    if (t < 8) {
        float m = -1e30f;
#pragma unroll
        for (int w = 0; w < 16; ++w) m = fmaxf(m, tbl[w * 24 + t]);
        tauS[t] = m - 1.0f;
    }
    __syncthreads();

    float tau[8];
#pragma unroll
    for (int r = 0; r < 8; ++r) tau[r] = tauS[r];

    // ---- support-set iteration ----
    for (int it = 0; it < ITERS; ++it) {
#pragma unroll
        for (int r = 0; r < 8; ++r) {
            float n = 0.f, s1 = 0.f, s2 = 0.f;
            float4 x0;
            if (r < 3)      x0 = *(const float4*)&zL[r * 4096 + c0];
            else            x0 = accA[r - 3];
            SCAN_F4(x0, tau[r]);
            SCAN_F4(accB[r], tau[r]);
#pragma unroll
            for (int off = 32; off; off >>= 1) {
                n  += __shfl_xor(n,  off, 64);
                s1 += __shfl_xor(s1, off, 64);
                s2 += __shfl_xor(s2, off, 64);
            }
            if (lane == 0) {
                tbl[wid * 24 + r * 3 + 0] = n;
                tbl[wid * 24 + r * 3 + 1] = s1;
                tbl[wid * 24 + r * 3 + 2] = s2;
            }
        }
        __syncthreads();
        if (t < 8) {
            float n = 0.f, s1 = 0.f, s2 = 0.f;
#pragma unroll
            for (int w = 0; w < 16; ++w) {
                n  += tbl[w * 24 + t * 3 + 0];
                s1 += tbl[w * 24 + t * 3 + 1];
                s2 += tbl[w * 24 + t * 3 + 2];
            }
            const float tcur = tauS[t];
            const float disc = s1 * s1 - n * (s2 - 1.0f);
            float tn;
            if (disc >= 0.0f) {
                tn = (s1 - sqrtf(disc)) / n;       // exact solve on current support
            } else {
                const float g = s1 - n * tcur;     // > 0 (support nonempty)
                const float f = s2 - tcur * (2.0f * s1 - n * tcur);
                tn = tcur + (f - 1.0f) / (2.0f * g);   // Newton fallback
            }
            tauS[t] = tn;
        }
        __syncthreads();
        bool same = true;
#pragma unroll
        for (int r = 0; r < 8; ++r) {
            const float nt = tauS[r];
            same &= (nt == tau[r]);
            tau[r] = nt;
        }
        if (same) break;   // block-uniform: all threads read identical tauS
    }

    // ---- p = max(z - tau, 0)^2, single write ----
#pragma unroll
    for (int r = 0; r < 8; ++r) {
        float4 x0;
        if (r < 3)      x0 = *(const float4*)&zL[r * 4096 + c0];
        else            x0 = accA[r - 3];
        float4 p0, p1;
        P2_F4(x0, p0, tau[r]);
        P2_F4(accB[r], p1, tau[r]);
        float* op = out + (size_t)(r0 + r) * 8192;
        *(float4*)(op + c0)        = p0;
        *(float4*)(op + c0 + 4096) = p1;
    }
}

// ---------------------------------------------------------------------------
extern "C" void kernel_launch(void* const* d_in, const int* in_sizes, int n_in,
                              void* d_out, int out_size, void* d_ws, size_t ws_size,
                              hipStream_t stream)
{
    const float* edge_repr = (const float*)d_in[0];
    const float* sub_repr  = (const float*)d_in[1];
    const float* W_sub     = (const float*)d_in[2];
    const float* b_sub     = (const float*)d_in[3];
    const float* W_edge    = (const float*)d_in[4];
    const float* b_edge    = (const float*)d_in[5];
    const float* log_scale = (const float*)d_in[6];
    float* out = (float*)d_out;

    float* sub_proj = (float*)d_ws;                      // [8192][64]  row-major
    float* edgeT    = (float*)d_ws + (size_t)8192 * 64;  // [64][8192]  k-major

    proj_norm_kernel<<<dim3(128, 2), 256, 0, stream>>>(
        sub_repr, edge_repr, W_sub, b_sub, W_edge, b_edge, sub_proj, edgeT);

    fused_score_entmax_kernel<<<1024, 1024, 0, stream>>>(
        sub_proj, edgeT, log_scale, out);
}